// Round 17
// baseline (336.924 us; speedup 1.0000x reference)
//
#include <hip/hip_runtime.h>
#include <hip/hip_bf16.h>

#define B_ 4
#define T_ 2048
#define C_ 1024
#define H_ 16
#define D_ 64
#define M_ (B_*T_)   // 8192

typedef __bf16 bf16x8 __attribute__((ext_vector_type(8)));
typedef float  f32x4  __attribute__((ext_vector_type(4)));
typedef float  f32x16 __attribute__((ext_vector_type(16)));
typedef int    i32x2v __attribute__((ext_vector_type(2)));

static __device__ __forceinline__ f32x4 mfma16(bf16x8 a, bf16x8 b, f32x4 c){
  return __builtin_amdgcn_mfma_f32_16x16x32_bf16(a, b, c, 0, 0, 0);
}
static __device__ __forceinline__ f32x16 mfma32(bf16x8 a, bf16x8 b, f32x16 c){
  return __builtin_amdgcn_mfma_f32_32x32x16_bf16(a, b, c, 0, 0, 0);
}

typedef const __attribute__((address_space(1))) void gas_void;
typedef __attribute__((address_space(3))) void las_void;
static __device__ __forceinline__ void gload_lds16(const void* g, const void* l){
  __builtin_amdgcn_global_load_lds((gas_void*)(unsigned long long)g,
                                   (las_void*)(unsigned int)(unsigned long long)l,
                                   16, 0, 0);
}

static __device__ __forceinline__ unsigned short f2bf(float f){
  union { float f; unsigned int i; } v; v.f = f;
  return (unsigned short)((v.i + 0x7fffu + ((v.i >> 16) & 1u)) >> 16);
}
static __device__ __forceinline__ unsigned cvtpk(float lo, float hi){
  unsigned r; asm("v_cvt_pk_bf16_f32 %0, %1, %2" : "=v"(r) : "v"(lo), "v"(hi)); return r;
}
static __device__ __forceinline__ float ex2(float x){ return __builtin_amdgcn_exp2f(x); }

#define SCALE_Q (0.125f * 1.4426950408889634f)

// ---------------- fused f32 -> bf16 convert: x + Wq/Wk/Wv/Wo ----------------
__global__ __launch_bounds__(256)
void convert_all_k(const float* __restrict__ x,
                   const float* __restrict__ wq, const float* __restrict__ wk,
                   const float* __restrict__ wv, const float* __restrict__ wo,
                   unsigned short* __restrict__ dst)
{
  const int NX = (int)((size_t)M_*C_/8);    // 1048576
  const int NW = (int)((size_t)C_*C_/8);    // 131072
  int i = blockIdx.x * 256 + threadIdx.x;
  const float* src; unsigned short* dp; int o;
  if (i < NX){ src = x; dp = dst; o = i; }
  else {
    int j = i - NX; int rgn = j / NW; o = j - rgn*NW;
    src = rgn==0?wq : rgn==1?wk : rgn==2?wv : wo;
    dp  = dst + (size_t)M_*C_ + (size_t)rgn*C_*C_;
  }
  const float4* s = (const float4*)(src + (size_t)o*8);
  float4 a = s[0], b = s[1];
  unsigned short ov[8] = { f2bf(a.x), f2bf(a.y), f2bf(a.z), f2bf(a.w),
                           f2bf(b.x), f2bf(b.y), f2bf(b.z), f2bf(b.w) };
  *(uint4*)(dp + (size_t)o*8) = *(const uint4*)ov;
}

// ---------------- GEMM v7: barrier-free 1-wave blocks, 64x64 tile, BK=32 ----------
// One wave per block -> global_load_lds + counted vmcnt are wave-local: NO barriers.
// 3 LDS buffers (24KB) rotate {read kt | in-flight kt+1 | staging kt+2} (disjoint).
// Subtile-lane LDS order -> zero-conflict ds_read_b128. XCD-aware swizzle.
// MODE 0: fused QKV (NBx=48): n<1024 -> Q (scaled), n<2048 -> K, else Vt.
// MODE 2: out-proj (NBx=16), f32 out.
template<int MODE>
__global__ __launch_bounds__(64)
void gemm_wave_k(const unsigned short* __restrict__ A,
                 const unsigned short* __restrict__ W,
                 const float* __restrict__ b0p, const float* __restrict__ b1p,
                 const float* __restrict__ b2p,
                 void* __restrict__ Cout_v)
{
  constexpr int NBx = (MODE == 0) ? 48 : 16;
  __shared__ alignas(16) unsigned short As[3][2048];   // 3 x 4KB (64r x 32k bf16)
  __shared__ alignas(16) unsigned short Bs[3][2048];
  const int lane = threadIdx.x & 63;
  const int g = lane >> 4, r = lane & 15;

  // XCD-aware swizzle (bijective: gridDim.x % 8 == 0)
  const int nwg  = gridDim.x;
  const int wgid = blockIdx.x;
  const int swz  = (wgid & 7) * (nwg >> 3) + (wgid >> 3);
  const int m0 = (swz / NBx) * 64, n0 = (swz % NBx) * 64;

  // subtile-lane staging: chunk i*64+lane -> row i*16 + r, kcol g*8 (16B)
  const unsigned short* Ap = &A[(size_t)(m0 + r)*C_ + g*8];
  const unsigned short* Wp = &W[(size_t)(n0 + r)*C_ + g*8];

  auto stage = [&](int buf, int kt){
    #pragma unroll
    for (int i = 0; i < 4; ++i)
      gload_lds16(Ap + (size_t)i*16*C_ + kt*32, &As[buf][(i*64 + lane)*8]);
    #pragma unroll
    for (int i = 0; i < 4; ++i)
      gload_lds16(Wp + (size_t)i*16*C_ + kt*32, &Bs[buf][(i*64 + lane)*8]);
  };

  f32x4 acc[4][4] = {};
  stage(0, 0); stage(1, 1);           // 16 loads in flight

  #pragma unroll 1
  for (int kt = 0; kt < 32; ++kt){
    const int cur = kt % 3;
    if (kt + 2 < 32){
      int nb = cur + 2; if (nb >= 3) nb -= 3;
      stage(nb, kt + 2);                                  // 24 in flight
      asm volatile("s_waitcnt vmcnt(16)" ::: "memory");   // kt's 8 landed
    } else if (kt + 1 < 32){
      asm volatile("s_waitcnt vmcnt(8)" ::: "memory");    // kt landed; kt+1 in flight
    } else {
      asm volatile("s_waitcnt vmcnt(0)" ::: "memory");
    }
    bf16x8 af[4], bfv[4];
    #pragma unroll
    for (int mf = 0; mf < 4; ++mf)
      af[mf] = *(const bf16x8*)&As[cur][mf*512 + lane*8];
    #pragma unroll
    for (int nf = 0; nf < 4; ++nf)
      bfv[nf] = *(const bf16x8*)&Bs[cur][nf*512 + lane*8];
    __builtin_amdgcn_s_setprio(1);
    #pragma unroll
    for (int mf = 0; mf < 4; ++mf)
      #pragma unroll
      for (int nf = 0; nf < 4; ++nf)
        acc[mf][nf] = mfma16(af[mf], bfv[nf], acc[mf][nf]);
    __builtin_amdgcn_s_setprio(0);
  }

  const int which = (MODE == 0) ? (n0 >> 10) : 0;
  const float* bp = (MODE == 0) ? (which==0 ? b0p : (which==1 ? b1p : b2p)) : b0p;
  const float scale = (MODE == 0 && which == 0) ? SCALE_Q : 1.0f;

  float bv[4];
  #pragma unroll
  for (int nf = 0; nf < 4; ++nf) bv[nf] = bp[(n0 + nf*16 + r) & 1023];

  #pragma unroll
  for (int mf = 0; mf < 4; ++mf){
    #pragma unroll
    for (int nf = 0; nf < 4; ++nf){
      int n = n0 + nf*16 + r;
      #pragma unroll
      for (int j = 0; j < 4; ++j){
        int m = m0 + mf*16 + g*4 + j;
        float val = (acc[mf][nf][j] + bv[nf]) * scale;
        if (MODE == 2){
          ((float*)Cout_v)[(size_t)m*C_ + n] = val;
        } else {
          int nn = n & 1023;
          int b = m >> 11, t = m & (T_-1), hgl = nn >> 6, d = nn & 63;
          size_t addr;
          if (which <= 1) addr = (size_t)which*M_*C_ + ((((size_t)b*H_ + hgl)*T_ + t) << 6) + d;
          else            addr = (size_t)2*M_*C_ + (((size_t)b*H_ + hgl)*D_ + d)*T_ + t;
          ((unsigned short*)Cout_v)[addr] = f2bf(val);
        }
      }
    }
  }
}

// ---------------- Flash attention v7: single-coverage pairing, 4 waves x 32q --------
// Q[B,H,T,D] (pre-scaled), K[B,H,T,D], Vt[B,H,D,T] -> ctx[B,T,C] bf16
// 16 q-blocks of 128 rows per bh; block pr handles q-blocks pr and 15-pr (bijective,
// uniform 34 wave-tiles). grid 512 x 256 thr; wgid = pr*64 + bh (XCD = bh%8).
__global__ __launch_bounds__(256, 2)
void attn_k(const unsigned short* __restrict__ Q,
            const unsigned short* __restrict__ K,
            const unsigned short* __restrict__ Vt,
            unsigned short* __restrict__ ctx)
{
  __shared__ alignas(16) unsigned short smem[2][2][64*64];   // [K/V][buf] 32 KB
  const int tid  = threadIdx.x;
  const int lane = tid & 63, w = tid >> 6;   // 4 warps
  const int h    = lane >> 5;
  const int ql   = lane & 31;
  const int wgid = blockIdx.x;
  const int pr   = wgid >> 6;                // 0..7
  const int bh   = wgid & 63;
  const size_t base = (size_t)bh * T_ * D_;
  const int bb = bh >> 4, hh = bh & 15;

  // stage 64x64 K + V tiles: 512 chunks, 2 per thread per array (subtile-lane order)
  auto stageKV = [&](int buf, int kv0){
    #pragma unroll
    for (int i = 0; i < 2; ++i){
      int cc = tid + i*256;
      int t2 = cc >> 8, k2 = (cc >> 6) & 3, l = cc & 63;
      int h2 = l >> 5, q2 = l & 31;
      gload_lds16(&K [base + (size_t)(kv0 + t2*32 + q2)*D_ + k2*16 + h2*8], &smem[0][buf][cc*8]);
      gload_lds16(&Vt[base + (size_t)(t2*32 + q2)*T_ + kv0 + k2*16 + h2*8], &smem[1][buf][cc*8]);
    }
  };

  #pragma unroll 1
  for (int hf = 0; hf < 2; ++hf){
    const int qb     = hf ? (15 - pr) : pr;  // 128-row q-block, each covered ONCE
    const int qlo    = qb*128 + w*32;        // this warp's 32 q-rows
    const int own_nt = (qlo >> 6) + 1;
    const int NT     = qb*2 + 2;

    bf16x8 qf[4];
    #pragma unroll
    for (int kc = 0; kc < 4; ++kc)
      qf[kc] = *(const bf16x8*)&Q[base + (size_t)(qlo + ql)*D_ + kc*16 + h*8];

    f32x16 oacc[2] = {};
    float m_run = -1e30f, l_run = 0.f;

    stageKV(0, 0);
    for (int kv = 0; kv < NT; ++kv){
      const int cur = kv & 1;
      if (kv + 1 < NT){
        stageKV(cur^1, (kv+1)*64);
        asm volatile("s_waitcnt vmcnt(4)" ::: "memory");   // tile kv landed; kv+1 in flight
      } else {
        asm volatile("s_waitcnt vmcnt(0)" ::: "memory");
      }
      __builtin_amdgcn_s_barrier();

      if (kv < own_nt){
        const bool partial = (kv == own_nt - 1);
        const unsigned short* Kb = &smem[0][cur][0];
        const unsigned short* Vb = &smem[1][cur][0];
        f32x16 st[2] = {};
        __builtin_amdgcn_s_setprio(1);
        #pragma unroll
        for (int t = 0; t < 2; ++t)
          #pragma unroll
          for (int kc = 0; kc < 4; ++kc){
            bf16x8 kfr = *(const bf16x8*)&Kb[(t*4 + kc)*512 + lane*8];
            st[t] = mfma32(kfr, qf[kc], st[t]);
          }
        __builtin_amdgcn_s_setprio(0);
        if (partial){
          #pragma unroll
          for (int t = 0; t < 2; ++t)
            #pragma unroll
            for (int rg = 0; rg < 16; ++rg){
              int kvi = kv*64 + t*32 + (rg&3) + 8*(rg>>2) + 4*h;
              if (kvi > qlo + ql) st[t][rg] = -1e30f;
            }
        }
        float a0 = st[0][0], a1 = st[0][1], a2 = st[0][2], a3 = st[0][3];
        #pragma unroll
        for (int i = 4; i < 16; i += 4){
          a0 = fmaxf(a0, st[0][i]);   a1 = fmaxf(a1, st[0][i+1]);
          a2 = fmaxf(a2, st[0][i+2]); a3 = fmaxf(a3, st[0][i+3]);
        }
        #pragma unroll
        for (int i = 0; i < 16; i += 4){
          a0 = fmaxf(a0, st[1][i]);   a1 = fmaxf(a1, st[1][i+1]);
          a2 = fmaxf(a2, st[1][i+2]); a3 = fmaxf(a3, st[1][i+3]);
        }
        float mx = fmaxf(fmaxf(a0, a1), fmaxf(a2, a3));
        mx = fmaxf(mx, __shfl_xor(mx, 32, 64));
        if (__any(mx - m_run > 8.0f)){
          float mnew  = fmaxf(m_run, mx);
          float alpha = ex2(m_run - mnew);
          l_run *= alpha;
          oacc[0] = oacc[0] * alpha;
          oacc[1] = oacc[1] * alpha;
          m_run = mnew;
        }
        float s0 = 0.f, s1 = 0.f, s2 = 0.f, s3 = 0.f;
        #pragma unroll
        for (int t = 0; t < 2; ++t)
          #pragma unroll
          for (int i = 0; i < 16; i += 4){
            st[t][i]   = ex2(st[t][i]   - m_run); s0 += st[t][i];
            st[t][i+1] = ex2(st[t][i+1] - m_run); s1 += st[t][i+1];
            st[t][i+2] = ex2(st[t][i+2] - m_run); s2 += st[t][i+2];
            st[t][i+3] = ex2(st[t][i+3] - m_run); s3 += st[t][i+3];
          }
        float rs = (s0 + s1) + (s2 + s3);
        rs += __shfl_xor(rs, 32, 64);
        l_run += rs;
        bf16x8 pf[4];
        #pragma unroll
        for (int t = 0; t < 2; ++t)
          #pragma unroll
          for (int cl = 0; cl < 2; ++cl){
            int b0 = cl*8;
            unsigned pkA = cvtpk(st[t][b0+0], st[t][b0+1]);
            unsigned pkB = cvtpk(st[t][b0+4], st[t][b0+5]);
            unsigned pkC = cvtpk(st[t][b0+2], st[t][b0+3]);
            unsigned pkD = cvtpk(st[t][b0+6], st[t][b0+7]);
            i32x2v r02 = __builtin_amdgcn_permlane32_swap((int)pkA, (int)pkB, false, false);
            i32x2v r13 = __builtin_amdgcn_permlane32_swap((int)pkC, (int)pkD, false, false);
            union { int d[4]; bf16x8 v; } u;
            u.d[0] = r02[0]; u.d[1] = r13[0]; u.d[2] = r02[1]; u.d[3] = r13[1];
            pf[t*2+cl] = u.v;
          }
        __builtin_amdgcn_s_setprio(1);
        #pragma unroll
        for (int dt = 0; dt < 2; ++dt)
          #pragma unroll
          for (int c = 0; c < 4; ++c){
            bf16x8 vfr = *(const bf16x8*)&Vb[(dt*4 + c)*512 + lane*8];
            oacc[dt] = mfma32(vfr, pf[c], oacc[dt]);
          }
        __builtin_amdgcn_s_setprio(0);
      }
      __builtin_amdgcn_s_barrier();
    }

    float inv = __builtin_amdgcn_rcpf(l_run);
    unsigned short* ob = &smem[0][0][0] + w*2048;   // 4 warps x 4KB, aliases K bufs
    #pragma unroll
    for (int dt = 0; dt < 2; ++dt)
      #pragma unroll
      for (int rg = 0; rg < 16; rg += 2){
        int d = dt*32 + (rg&3) + 8*(rg>>2) + 4*h;
        unsigned pk = cvtpk(oacc[dt][rg]*inv, oacc[dt][rg+1]*inv);
        int off = (ql*128 + d*2) ^ ((ql&7)<<4);
        *(unsigned*)((char*)ob + off) = pk;
      }
    __builtin_amdgcn_s_waitcnt(0);  // lgkmcnt(0): same-wave LDS visibility
    const size_t orow = ((size_t)bb*T_ + qlo + ql)*C_ + hh*64 + h*32;
    #pragma unroll
    for (int x = 0; x < 4; ++x){
      int off = (ql*128 + h*64 + x*16) ^ ((ql&7)<<4);
      bf16x8 v = *(const bf16x8*)((const char*)ob + off);
      *(bf16x8*)&ctx[orow + x*8] = v;
    }
    __syncthreads();   // obuf reads done before next phase restages K/V
  }
}

extern "C" void kernel_launch(void* const* d_in, const int* in_sizes, int n_in,
                              void* d_out, int out_size, void* d_ws, size_t ws_size,
                              hipStream_t stream)
{
  const float* x  = (const float*)d_in[0];
  const float* Wq = (const float*)d_in[1];
  const float* bq = (const float*)d_in[2];
  const float* Wk = (const float*)d_in[3];
  const float* bk = (const float*)d_in[4];
  const float* Wv = (const float*)d_in[5];
  const float* bv = (const float*)d_in[6];
  const float* Wo = (const float*)d_in[7];
  const float* bo = (const float*)d_in[8];
  float* out = (float*)d_out;

  const size_t NELT = (size_t)M_ * C_;   // 8.39M
  const size_t WELT = (size_t)C_ * C_;   // 1.05M
  unsigned short* xb  = (unsigned short*)d_ws;
  unsigned short* Wcb = xb  + NELT;          // Wq|Wk|Wv|Wo concat (bf16)
  unsigned short* Wob = Wcb + 3*WELT;
  unsigned short* Qb  = Wob + WELT;          // Q | K | Vt contiguous
  unsigned short* Kb  = Qb  + NELT;
  unsigned short* Vtb = Kb  + NELT;
  unsigned short* ctx = Vtb + NELT;

  convert_all_k<<<dim3((unsigned)((NELT + 4*WELT)/8/256)), 256, 0, stream>>>(x, Wq, Wk, Wv, Wo, xb);

  gemm_wave_k<0><<<dim3(6144), 64, 0, stream>>>(xb, Wcb, bq, bk, bv, Qb);   // 128 x 48
  attn_k<<<dim3(512), 256, 0, stream>>>(Qb, Kb, Vtb, ctx);
  gemm_wave_k<2><<<dim3(2048), 64, 0, stream>>>(ctx, Wob, bo, bo, bo, out); // 128 x 16
}

// Round 18
// 204.188 us; speedup vs baseline: 1.6501x; 1.6501x over previous
//
#include <hip/hip_runtime.h>
#include <hip/hip_bf16.h>

#define B_ 4
#define T_ 2048
#define C_ 1024
#define H_ 16
#define D_ 64
#define M_ (B_*T_)   // 8192

typedef __bf16 bf16x8 __attribute__((ext_vector_type(8)));
typedef float  f32x4  __attribute__((ext_vector_type(4)));
typedef float  f32x16 __attribute__((ext_vector_type(16)));
typedef int    i32x2v __attribute__((ext_vector_type(2)));

static __device__ __forceinline__ f32x4 mfma16(bf16x8 a, bf16x8 b, f32x4 c){
  return __builtin_amdgcn_mfma_f32_16x16x32_bf16(a, b, c, 0, 0, 0);
}
static __device__ __forceinline__ f32x16 mfma32(bf16x8 a, bf16x8 b, f32x16 c){
  return __builtin_amdgcn_mfma_f32_32x32x16_bf16(a, b, c, 0, 0, 0);
}

typedef const __attribute__((address_space(1))) void gas_void;
typedef __attribute__((address_space(3))) void las_void;
static __device__ __forceinline__ void gload_lds16(const void* g, const void* l){
  __builtin_amdgcn_global_load_lds((gas_void*)(unsigned long long)g,
                                   (las_void*)(unsigned int)(unsigned long long)l,
                                   16, 0, 0);
}

static __device__ __forceinline__ unsigned short f2bf(float f){
  union { float f; unsigned int i; } v; v.f = f;
  return (unsigned short)((v.i + 0x7fffu + ((v.i >> 16) & 1u)) >> 16);
}
static __device__ __forceinline__ unsigned cvtpk(float lo, float hi){
  unsigned r; asm("v_cvt_pk_bf16_f32 %0, %1, %2" : "=v"(r) : "v"(lo), "v"(hi)); return r;
}
static __device__ __forceinline__ float ex2(float x){ return __builtin_amdgcn_exp2f(x); }

#define SCALE_Q (0.125f * 1.4426950408889634f)

// ---------------- fused f32 -> bf16 convert: x + Wq/Wk/Wv/Wo ----------------
__global__ __launch_bounds__(256)
void convert_all_k(const float* __restrict__ x,
                   const float* __restrict__ wq, const float* __restrict__ wk,
                   const float* __restrict__ wv, const float* __restrict__ wo,
                   unsigned short* __restrict__ dst)
{
  const int NX = (int)((size_t)M_*C_/8);    // 1048576
  const int NW = (int)((size_t)C_*C_/8);    // 131072
  int i = blockIdx.x * 256 + threadIdx.x;
  const float* src; unsigned short* dp; int o;
  if (i < NX){ src = x; dp = dst; o = i; }
  else {
    int j = i - NX; int rgn = j / NW; o = j - rgn*NW;
    src = rgn==0?wq : rgn==1?wk : rgn==2?wv : wo;
    dp  = dst + (size_t)M_*C_ + (size_t)rgn*C_*C_;
  }
  const float4* s = (const float4*)(src + (size_t)o*8);
  float4 a = s[0], b = s[1];
  unsigned short ov[8] = { f2bf(a.x), f2bf(a.y), f2bf(a.z), f2bf(a.w),
                           f2bf(b.x), f2bf(b.y), f2bf(b.z), f2bf(b.w) };
  *(uint4*)(dp + (size_t)o*8) = *(const uint4*)ov;
}

// ---------------- GEMM (R11-proven body) + XCD-aware block swizzle ----------------
// 128x128, 4 waves, BK=32, dbuf + syncthreads. 1D grid; wgid -> XCD-contiguous chunk
// (n fastest within chunk -> A-panel reuse stays in one XCD's L2).
// MODE 0: fused QKV (NBx=24): n<1024 -> Q (scaled), n<2048 -> K, else Vt.
// MODE 2: out-proj (NBx=8), f32 out.
// NOTE: no setprio here — lockstep multi-wave GEMM measured ~20% slower with it
// (R8/R9/R10/R14/R15 all ~120-134us with setprio vs 105us without; cf. m190).
template<int MODE>
__global__ __launch_bounds__(256)
void gemm_bias_k(const unsigned short* __restrict__ A,
                 const unsigned short* __restrict__ W,
                 const float* __restrict__ b0p, const float* __restrict__ b1p,
                 const float* __restrict__ b2p,
                 void* __restrict__ Cout_v)
{
  constexpr int TM = 128, BK = 32;
  constexpr int NBx = (MODE == 0) ? 24 : 8;
  __shared__ alignas(16) unsigned short As[2][TM*BK];
  __shared__ alignas(16) unsigned short Bs[2][TM*BK];
  const int tid = threadIdx.x;
  const int lane = tid & 63;
  const int wid  = tid >> 6;
  const int wm = wid >> 1, wn = wid & 1;
  const int g = lane >> 4, r = lane & 15;

  // XCD-aware swizzle (bijective: gridDim.x % 8 == 0)
  const int nwg  = gridDim.x;
  const int wgid = blockIdx.x;
  const int swz  = (wgid & 7) * (nwg >> 3) + (wgid >> 3);
  const int m0 = (swz / NBx) * TM, n0 = (swz % NBx) * TM;

  f32x4 acc[4][4] = {};

  auto stage = [&](int buf, int kt){
    #pragma unroll
    for (int i = 0; i < 2; ++i){
      int c = tid + i*256;
      int row = c >> 2, col = (c & 3) << 3;
      gload_lds16(&A[(size_t)(m0+row)*C_ + kt*BK + col], &As[buf][c*8]);
    }
    #pragma unroll
    for (int i = 0; i < 2; ++i){
      int c = tid + i*256;
      int row = c >> 2, col = (c & 3) << 3;
      gload_lds16(&W[(size_t)(n0+row)*C_ + kt*BK + col], &Bs[buf][c*8]);
    }
  };

  stage(0, 0);
  const int nkt = C_/BK;
  for (int kt = 0; kt < nkt; ++kt){
    int cur = kt & 1;
    if (kt + 1 < nkt) stage(cur^1, kt+1);
    __syncthreads();
    bf16x8 af[4], bfv[4];
    #pragma unroll
    for (int mf = 0; mf < 4; ++mf)
      af[mf] = *(const bf16x8*)&As[cur][(wm*64 + mf*16 + r)*BK + g*8];
    #pragma unroll
    for (int nf = 0; nf < 4; ++nf)
      bfv[nf] = *(const bf16x8*)&Bs[cur][(wn*64 + nf*16 + r)*BK + g*8];
    #pragma unroll
    for (int mf = 0; mf < 4; ++mf)
      #pragma unroll
      for (int nf = 0; nf < 4; ++nf)
        acc[mf][nf] = mfma16(af[mf], bfv[nf], acc[mf][nf]);
    __syncthreads();
  }

  const int which = (MODE == 0) ? (n0 >> 10) : 0;
  const float* bp = (MODE == 0) ? (which==0 ? b0p : (which==1 ? b1p : b2p)) : b0p;
  const float scale = (MODE == 0 && which == 0) ? SCALE_Q : 1.0f;

  float bv[4];
  #pragma unroll
  for (int nf = 0; nf < 4; ++nf) bv[nf] = bp[(n0 + wn*64 + nf*16 + r) & 1023];

  #pragma unroll
  for (int mf = 0; mf < 4; ++mf){
    #pragma unroll
    for (int nf = 0; nf < 4; ++nf){
      int n = n0 + wn*64 + nf*16 + r;
      #pragma unroll
      for (int j = 0; j < 4; ++j){
        int m = m0 + wm*64 + mf*16 + g*4 + j;
        float val = (acc[mf][nf][j] + bv[nf]) * scale;
        if (MODE == 2){
          ((float*)Cout_v)[(size_t)m*C_ + n] = val;
        } else {
          int nn = n & 1023;
          int b = m >> 11, t = m & (T_-1), hgl = nn >> 6, d = nn & 63;
          size_t addr;
          if (which <= 1) addr = (size_t)which*M_*C_ + ((((size_t)b*H_ + hgl)*T_ + t) << 6) + d;
          else            addr = (size_t)2*M_*C_ + (((size_t)b*H_ + hgl)*D_ + d)*T_ + t;
          ((unsigned short*)Cout_v)[addr] = f2bf(val);
        }
      }
    }
  }
}

// ---------------- Flash attention v7: single-coverage pairing, 4 waves x 32q --------
// Q[B,H,T,D] (pre-scaled), K[B,H,T,D], Vt[B,H,D,T] -> ctx[B,T,C] bf16
// 16 q-blocks of 128 rows per bh; block pr handles q-blocks pr and 15-pr (bijective,
// uniform 34 wave-tiles). grid 512 x 256 thr; wgid = pr*64 + bh (XCD = bh%8).
__global__ __launch_bounds__(256, 2)
void attn_k(const unsigned short* __restrict__ Q,
            const unsigned short* __restrict__ K,
            const unsigned short* __restrict__ Vt,
            unsigned short* __restrict__ ctx)
{
  __shared__ alignas(16) unsigned short smem[2][2][64*64];   // [K/V][buf] 32 KB
  const int tid  = threadIdx.x;
  const int lane = tid & 63, w = tid >> 6;   // 4 warps
  const int h    = lane >> 5;
  const int ql   = lane & 31;
  const int wgid = blockIdx.x;
  const int pr   = wgid >> 6;                // 0..7
  const int bh   = wgid & 63;
  const size_t base = (size_t)bh * T_ * D_;
  const int bb = bh >> 4, hh = bh & 15;

  // stage 64x64 K + V tiles: 512 chunks, 2 per thread per array (subtile-lane order)
  auto stageKV = [&](int buf, int kv0){
    #pragma unroll
    for (int i = 0; i < 2; ++i){
      int cc = tid + i*256;
      int t2 = cc >> 8, k2 = (cc >> 6) & 3, l = cc & 63;
      int h2 = l >> 5, q2 = l & 31;
      gload_lds16(&K [base + (size_t)(kv0 + t2*32 + q2)*D_ + k2*16 + h2*8], &smem[0][buf][cc*8]);
      gload_lds16(&Vt[base + (size_t)(t2*32 + q2)*T_ + kv0 + k2*16 + h2*8], &smem[1][buf][cc*8]);
    }
  };

  #pragma unroll 1
  for (int hf = 0; hf < 2; ++hf){
    const int qb     = hf ? (15 - pr) : pr;  // 128-row q-block, each covered ONCE
    const int qlo    = qb*128 + w*32;        // this warp's 32 q-rows
    const int own_nt = (qlo >> 6) + 1;
    const int NT     = qb*2 + 2;

    bf16x8 qf[4];
    #pragma unroll
    for (int kc = 0; kc < 4; ++kc)
      qf[kc] = *(const bf16x8*)&Q[base + (size_t)(qlo + ql)*D_ + kc*16 + h*8];

    f32x16 oacc[2] = {};
    float m_run = -1e30f, l_run = 0.f;

    stageKV(0, 0);
    for (int kv = 0; kv < NT; ++kv){
      const int cur = kv & 1;
      if (kv + 1 < NT){
        stageKV(cur^1, (kv+1)*64);
        asm volatile("s_waitcnt vmcnt(4)" ::: "memory");   // tile kv landed; kv+1 in flight
      } else {
        asm volatile("s_waitcnt vmcnt(0)" ::: "memory");
      }
      __builtin_amdgcn_s_barrier();

      if (kv < own_nt){
        const bool partial = (kv == own_nt - 1);
        const unsigned short* Kb = &smem[0][cur][0];
        const unsigned short* Vb = &smem[1][cur][0];
        f32x16 st[2] = {};
        __builtin_amdgcn_s_setprio(1);
        #pragma unroll
        for (int t = 0; t < 2; ++t)
          #pragma unroll
          for (int kc = 0; kc < 4; ++kc){
            bf16x8 kfr = *(const bf16x8*)&Kb[(t*4 + kc)*512 + lane*8];
            st[t] = mfma32(kfr, qf[kc], st[t]);
          }
        __builtin_amdgcn_s_setprio(0);
        if (partial){
          #pragma unroll
          for (int t = 0; t < 2; ++t)
            #pragma unroll
            for (int rg = 0; rg < 16; ++rg){
              int kvi = kv*64 + t*32 + (rg&3) + 8*(rg>>2) + 4*h;
              if (kvi > qlo + ql) st[t][rg] = -1e30f;
            }
        }
        float a0 = st[0][0], a1 = st[0][1], a2 = st[0][2], a3 = st[0][3];
        #pragma unroll
        for (int i = 4; i < 16; i += 4){
          a0 = fmaxf(a0, st[0][i]);   a1 = fmaxf(a1, st[0][i+1]);
          a2 = fmaxf(a2, st[0][i+2]); a3 = fmaxf(a3, st[0][i+3]);
        }
        #pragma unroll
        for (int i = 0; i < 16; i += 4){
          a0 = fmaxf(a0, st[1][i]);   a1 = fmaxf(a1, st[1][i+1]);
          a2 = fmaxf(a2, st[1][i+2]); a3 = fmaxf(a3, st[1][i+3]);
        }
        float mx = fmaxf(fmaxf(a0, a1), fmaxf(a2, a3));
        mx = fmaxf(mx, __shfl_xor(mx, 32, 64));
        if (__any(mx - m_run > 8.0f)){
          float mnew  = fmaxf(m_run, mx);
          float alpha = ex2(m_run - mnew);
          l_run *= alpha;
          oacc[0] = oacc[0] * alpha;
          oacc[1] = oacc[1] * alpha;
          m_run = mnew;
        }
        float s0 = 0.f, s1 = 0.f, s2 = 0.f, s3 = 0.f;
        #pragma unroll
        for (int t = 0; t < 2; ++t)
          #pragma unroll
          for (int i = 0; i < 16; i += 4){
            st[t][i]   = ex2(st[t][i]   - m_run); s0 += st[t][i];
            st[t][i+1] = ex2(st[t][i+1] - m_run); s1 += st[t][i+1];
            st[t][i+2] = ex2(st[t][i+2] - m_run); s2 += st[t][i+2];
            st[t][i+3] = ex2(st[t][i+3] - m_run); s3 += st[t][i+3];
          }
        float rs = (s0 + s1) + (s2 + s3);
        rs += __shfl_xor(rs, 32, 64);
        l_run += rs;
        bf16x8 pf[4];
        #pragma unroll
        for (int t = 0; t < 2; ++t)
          #pragma unroll
          for (int cl = 0; cl < 2; ++cl){
            int b0 = cl*8;
            unsigned pkA = cvtpk(st[t][b0+0], st[t][b0+1]);
            unsigned pkB = cvtpk(st[t][b0+4], st[t][b0+5]);
            unsigned pkC = cvtpk(st[t][b0+2], st[t][b0+3]);
            unsigned pkD = cvtpk(st[t][b0+6], st[t][b0+7]);
            i32x2v r02 = __builtin_amdgcn_permlane32_swap((int)pkA, (int)pkB, false, false);
            i32x2v r13 = __builtin_amdgcn_permlane32_swap((int)pkC, (int)pkD, false, false);
            union { int d[4]; bf16x8 v; } u;
            u.d[0] = r02[0]; u.d[1] = r13[0]; u.d[2] = r02[1]; u.d[3] = r13[1];
            pf[t*2+cl] = u.v;
          }
        __builtin_amdgcn_s_setprio(1);
        #pragma unroll
        for (int dt = 0; dt < 2; ++dt)
          #pragma unroll
          for (int c = 0; c < 4; ++c){
            bf16x8 vfr = *(const bf16x8*)&Vb[(dt*4 + c)*512 + lane*8];
            oacc[dt] = mfma32(vfr, pf[c], oacc[dt]);
          }
        __builtin_amdgcn_s_setprio(0);
      }
      __builtin_amdgcn_s_barrier();
    }

    float inv = __builtin_amdgcn_rcpf(l_run);
    unsigned short* ob = &smem[0][0][0] + w*2048;   // 4 warps x 4KB, aliases K bufs
    #pragma unroll
    for (int dt = 0; dt < 2; ++dt)
      #pragma unroll
      for (int rg = 0; rg < 16; rg += 2){
        int d = dt*32 + (rg&3) + 8*(rg>>2) + 4*h;
        unsigned pk = cvtpk(oacc[dt][rg]*inv, oacc[dt][rg+1]*inv);
        int off = (ql*128 + d*2) ^ ((ql&7)<<4);
        *(unsigned*)((char*)ob + off) = pk;
      }
    __builtin_amdgcn_s_waitcnt(0);  // lgkmcnt(0): same-wave LDS visibility
    const size_t orow = ((size_t)bb*T_ + qlo + ql)*C_ + hh*64 + h*32;
    #pragma unroll
    for (int x = 0; x < 4; ++x){
      int off = (ql*128 + h*64 + x*16) ^ ((ql&7)<<4);
      bf16x8 v = *(const bf16x8*)((const char*)ob + off);
      *(bf16x8*)&ctx[orow + x*8] = v;
    }
    __syncthreads();   // obuf reads done before next phase restages K/V
  }
}

extern "C" void kernel_launch(void* const* d_in, const int* in_sizes, int n_in,
                              void* d_out, int out_size, void* d_ws, size_t ws_size,
                              hipStream_t stream)
{
  const float* x  = (const float*)d_in[0];
  const float* Wq = (const float*)d_in[1];
  const float* bq = (const float*)d_in[2];
  const float* Wk = (const float*)d_in[3];
  const float* bk = (const float*)d_in[4];
  const float* Wv = (const float*)d_in[5];
  const float* bv = (const float*)d_in[6];
  const float* Wo = (const float*)d_in[7];
  const float* bo = (const float*)d_in[8];
  float* out = (float*)d_out;

  const size_t NELT = (size_t)M_ * C_;   // 8.39M
  const size_t WELT = (size_t)C_ * C_;   // 1.05M
  unsigned short* xb  = (unsigned short*)d_ws;
  unsigned short* Wcb = xb  + NELT;          // Wq|Wk|Wv|Wo concat (bf16)
  unsigned short* Wob = Wcb + 3*WELT;
  unsigned short* Qb  = Wob + WELT;          // Q | K | Vt contiguous
  unsigned short* Kb  = Qb  + NELT;
  unsigned short* Vtb = Kb  + NELT;
  unsigned short* ctx = Vtb + NELT;

  convert_all_k<<<dim3((unsigned)((NELT + 4*WELT)/8/256)), 256, 0, stream>>>(x, Wq, Wk, Wv, Wo, xb);

  gemm_bias_k<0><<<dim3(1536), 256, 0, stream>>>(xb, Wcb, bq, bk, bv, Qb);   // 24 x 64
  attn_k<<<dim3(512), 256, 0, stream>>>(Qb, Kb, Vtb, ctx);
  gemm_bias_k<2><<<dim3(512), 256, 0, stream>>>(ctx, Wob, bo, bo, bo, out);  // 8 x 64
}